// Round 19
// baseline (62.349 us; speedup 1.0000x reference)
//
#include <hip/hip_runtime.h>
#include <float.h>

// loss = (1/(E(E-1))) * sum_{i,j: t_i != t_j} relu(pred[i,t_j] - (f_own[j]-1)) / (N[t_i] N[t_j])
// Identity: sum_{k<S} relu(p - thr_k) = S*p - sum_{k<S} min(p, thr_k), slots >= cnt masked
// to FLT_MAX at load. Thread = class; 24 threshold slots in registers; rows coalesced.
// SINGLE static body (no switch/gate/fallback): R11/R15 evidence says the multi-path switch
// is what pins VGPR=64 (4 waves/SIMD); single body printed 32 (R15). Classes with cnt > 24
// (expected ~1) contribute slots [24, cnt) via a cheap row-parallel residual in k_final.
// Diagonal excluded in-loop. No same-address atomics.

#define CCLS 1000
#define PADF 64     // float slots per class (residual supports count <= 64)
#define TPB 256
#define CCH 250     // classes per chunk -> 4 chunks
#define NCH 4
#define NRBLK 512   // row blocks per chunk: RPB = 12288/512 = 24
#define NBLK (NCH * NRBLK)
#define RMAX 32
#define NQS 6       // static quads in k_main (24 slots)

__global__ void k_scatter(const float* __restrict__ pred, const int* __restrict__ target,
                          int* fill, float* thrP, int B) {
    int j = blockIdx.x * 256 + threadIdx.x;
    if (j >= B) return;
    int tj = target[j];
    float fo = pred[(size_t)j * CCLS + tj];  // f_own[j]
    int pos = atomicAdd(&fill[tj], 1);       // scattered addresses, low contention
    if (pos < PADF) thrP[tj * PADF + pos] = fo - 1.0f;
}

#define MIN4(p, t) ((fminf(p, t.x) + fminf(p, t.y)) + (fminf(p, t.z) + fminf(p, t.w)))

__global__ __launch_bounds__(TPB) void k_main(const float* __restrict__ pred,
        const int* __restrict__ target, const float* __restrict__ thrP,
        const int* __restrict__ fill,
        float* __restrict__ part, int B, int RPB) {
    __shared__ float2 rowWT[RMAX];   // (target_as_float, invN[target]) per row
    __shared__ float redL[TPB / 64];

    const int tid = threadIdx.x;
    const int chunk = blockIdx.x / NRBLK;
    const int rblk = blockIdx.x % NRBLK;
    const int c0 = chunk * CCH;
    const int rbase = rblk * RPB;
    const int rows = min(min(RPB, B - rbase), RMAX);

    for (int r = tid; r < rows; r += TPB) {
        int t = target[rbase + r];
        rowWT[r] = make_float2(__int_as_float(t), 1.0f / (float)fill[t]);
    }
    __syncthreads();

    const int ccS = min(tid, CCH - 1);
    const int c = c0 + ccS;
    const int cntR = fill[c];
    const int cnt = min(cntR, PADF);
    const float invc = (tid < CCH && cntR > 0) ? 1.0f / (float)cntR : 0.f;

    const float4* tp4 = (const float4*)(thrP + (size_t)c * PADF);
    const float* pp = pred + (size_t)rbase * CCLS + c;
    float acc = 0.f;

    // Load 6 quads, masking slots >= cnt to FLT_MAX (they contribute p, cancelled by fS*p).
    float4 tq[NQS];
#pragma unroll
    for (int q = 0; q < NQS; ++q) {
        float4 t = tp4[q];
        t.x = (4 * q + 0 < cnt) ? t.x : FLT_MAX;
        t.y = (4 * q + 1 < cnt) ? t.y : FLT_MAX;
        t.z = (4 * q + 2 < cnt) ? t.z : FLT_MAX;
        t.w = (4 * q + 3 < cnt) ? t.w : FLT_MAX;
        tq[q] = t;
    }
    const float fS = (float)(4 * NQS);

    int r = 0;
#pragma unroll 1
    for (; r + 4 <= rows; r += 4) {
        const float p0 = pp[(size_t)(r + 0) * CCLS];
        const float p1 = pp[(size_t)(r + 1) * CCLS];
        const float p2 = pp[(size_t)(r + 2) * CCLS];
        const float p3 = pp[(size_t)(r + 3) * CCLS];
        float a0 = 0.f, a1 = 0.f, a2 = 0.f, a3 = 0.f;
#pragma unroll
        for (int q = 0; q < NQS; ++q) {
            a0 += MIN4(p0, tq[q]);
            a1 += MIN4(p1, tq[q]);
            a2 += MIN4(p2, tq[q]);
            a3 += MIN4(p3, tq[q]);
        }
        const float2 w0 = rowWT[r + 0], w1 = rowWT[r + 1];
        const float2 w2 = rowWT[r + 2], w3 = rowWT[r + 3];
        const float s0 = (c != __float_as_int(w0.x)) ? w0.y : 0.f;
        const float s1 = (c != __float_as_int(w1.x)) ? w1.y : 0.f;
        const float s2 = (c != __float_as_int(w2.x)) ? w2.y : 0.f;
        const float s3 = (c != __float_as_int(w3.x)) ? w3.y : 0.f;
        acc = fmaf(fmaf(fS, p0, -a0), s0, acc);
        acc = fmaf(fmaf(fS, p1, -a1), s1, acc);
        acc = fmaf(fmaf(fS, p2, -a2), s2, acc);
        acc = fmaf(fmaf(fS, p3, -a3), s3, acc);
    }
    for (; r < rows; ++r) {
        const float p = pp[(size_t)r * CCLS];
        float a = 0.f;
#pragma unroll
        for (int q = 0; q < NQS; ++q) a += MIN4(p, tq[q]);
        const float2 w = rowWT[r];
        const float s = (c != __float_as_int(w.x)) ? w.y : 0.f;
        acc = fmaf(fmaf(fS, p, -a), s, acc);
    }
    acc *= invc;

    for (int o = 32; o; o >>= 1) acc += __shfl_down(acc, o);
    if ((tid & 63) == 0) redL[tid >> 6] = acc;
    __syncthreads();
    if (tid == 0) {
        float ssum = 0.f;
#pragma unroll
        for (int k = 0; k < TPB / 64; ++k) ssum += redL[k];
        part[blockIdx.x] = ssum;          // plain store, no contention
    }
}

// Single-block epilogue: partial reduce + E count + residual slots [24, cnt) for the
// (expected ~0-2) classes with cnt > 24. Row-parallel across 1024 threads; threshold
// reads are same-address broadcasts (L1-hot). No long dependent chains.
__global__ __launch_bounds__(1024) void k_final(const float* __restrict__ part,
        const int* __restrict__ fill, const float* __restrict__ thrP,
        const float* __restrict__ pred, const int* __restrict__ target, int B,
        float* __restrict__ out) {
    __shared__ float wP[16];
    __shared__ int wE[16];
    __shared__ int bigL[32];
    __shared__ int nbigS;
    const int tid = threadIdx.x;
    if (tid == 0) nbigS = 0;
    __syncthreads();

    float sp = 0.f;
    for (int i = tid; i < NBLK; i += 1024) sp += part[i];
    int se = 0;
    for (int c = tid; c < CCLS; c += 1024) {
        int f = fill[c];
        se += (f > 0) ? 1 : 0;
        if (f > 4 * NQS) {
            int idx = atomicAdd(&nbigS, 1);   // LDS atomic, tiny
            if (idx < 32) bigL[idx] = c;
        }
    }
    __syncthreads();

    const int nbig = min(nbigS, 32);
    for (int bi = 0; bi < nbig; ++bi) {
        const int c = bigL[bi];
        const int cntR = fill[c];
        const int cnt = min(cntR, PADF);
        const float invc = 1.0f / (float)cntR;
        for (int i = tid; i < B; i += 1024) {
            const int t = target[i];
            if (t == c) continue;
            const float p = pred[(size_t)i * CCLS + c];
            float a = 0.f;
            for (int k = 4 * NQS; k < cnt; ++k)
                a += fmaxf(p - thrP[(size_t)c * PADF + k], 0.f);
            sp += a * invc / (float)fill[t];
        }
    }

    for (int o = 32; o; o >>= 1) {
        sp += __shfl_down(sp, o);
        se += __shfl_down(se, o);
    }
    if ((tid & 63) == 0) { wP[tid >> 6] = sp; wE[tid >> 6] = se; }
    __syncthreads();
    if (tid == 0) {
        float tp = 0.f;
        int te = 0;
#pragma unroll
        for (int k = 0; k < 16; ++k) { tp += wP[k]; te += wE[k]; }
        float E = (float)te;
        out[0] = tp / (E * (E - 1.0f));
    }
}

extern "C" void kernel_launch(void* const* d_in, const int* in_sizes, int n_in,
                              void* d_out, int out_size, void* d_ws, size_t ws_size,
                              hipStream_t stream) {
    const float* pred = (const float*)d_in[0];
    const int* target = (const int*)d_in[1];
    const int B = in_sizes[1];  // 12288

    char* ws = (char*)d_ws;
    int* fill   = (int*)(ws + 0);        // 1000 ints
    float* part = (float*)(ws + 4096);   // 2048 floats
    float* thrP = (float*)(ws + 16384);  // 1000*64 floats (256KB)

    const int gb = (B + 255) / 256;
    const int RPB = (B + NRBLK - 1) / NRBLK;

    hipMemsetAsync(fill, 0, CCLS * sizeof(int), stream);
    k_scatter<<<gb, 256, 0, stream>>>(pred, target, fill, thrP, B);
    k_main<<<NBLK, TPB, 0, stream>>>(pred, target, thrP, fill, part, B, RPB);
    k_final<<<1, 1024, 0, stream>>>(part, fill, thrP, pred, target, B, (float*)d_out);
}

// Round 20
// 44.031 us; speedup vs baseline: 1.4160x; 1.4160x over previous
//
#include <hip/hip_runtime.h>
#include <float.h>

// loss = (1/(E(E-1))) * sum_{i,j: t_i != t_j} relu(pred[i,t_j] - (f_own[j]-1)) / (N[t_i] N[t_j])
// Identity: sum_{k<S} relu(p - thr_k) = S*p - sum_{k<S} min(p, thr_k), slots >= cnt masked
// to FLT_MAX at load. Thread = class; 24 threshold slots in registers (SINGLE static body,
// no switch -- multi-path switch pinned VGPR=64 in R11-R17). Classes with cnt > 24
// (expected ~1) contribute slots [24, cnt) via GRID-PARALLEL k_resid (R18 put this gather
// on one CU in k_final: +21 us). Diagonal excluded in-loop. No same-address atomics
// except one per big class in k_scatter (~1 total).

#define CCLS 1000
#define PADF 64     // float slots per class (residual supports count <= 64)
#define TPB 256
#define CCH 250     // classes per chunk -> 4 chunks
#define NCH 4
#define NRBLK 512   // row blocks per chunk: RPB = 12288/512 = 24
#define NBLK (NCH * NRBLK)
#define RMAX 32
#define NQS 6       // static quads in k_main (24 slots)
#define NRES 48     // k_resid blocks (48*256 = 12288 rows)
#define MAXBIG 32

__global__ void k_scatter(const float* __restrict__ pred, const int* __restrict__ target,
                          int* fill, float* thrP, int* bigN, int* bigList, int B) {
    int j = blockIdx.x * 256 + threadIdx.x;
    if (j >= B) return;
    int tj = target[j];
    float fo = pred[(size_t)j * CCLS + tj];  // f_own[j]
    int pos = atomicAdd(&fill[tj], 1);       // scattered addresses, low contention
    if (pos < PADF) thrP[tj * PADF + pos] = fo - 1.0f;
    if (pos == 4 * NQS) {                    // class crosses register capacity: record once
        int bi = atomicAdd(bigN, 1);
        if (bi < MAXBIG) bigList[bi] = tj;
    }
}

#define MIN4(p, t) ((fminf(p, t.x) + fminf(p, t.y)) + (fminf(p, t.z) + fminf(p, t.w)))

__global__ __launch_bounds__(TPB) void k_main(const float* __restrict__ pred,
        const int* __restrict__ target, const float* __restrict__ thrP,
        const int* __restrict__ fill,
        float* __restrict__ part, int B, int RPB) {
    __shared__ float2 rowWT[RMAX];   // (target_as_float, invN[target]) per row
    __shared__ float redL[TPB / 64];

    const int tid = threadIdx.x;
    const int chunk = blockIdx.x / NRBLK;
    const int rblk = blockIdx.x % NRBLK;
    const int c0 = chunk * CCH;
    const int rbase = rblk * RPB;
    const int rows = min(min(RPB, B - rbase), RMAX);

    for (int r = tid; r < rows; r += TPB) {
        int t = target[rbase + r];
        rowWT[r] = make_float2(__int_as_float(t), 1.0f / (float)fill[t]);
    }
    __syncthreads();

    const int ccS = min(tid, CCH - 1);
    const int c = c0 + ccS;
    const int cntR = fill[c];
    const int cnt = min(cntR, PADF);
    const float invc = (tid < CCH && cntR > 0) ? 1.0f / (float)cntR : 0.f;

    const float4* tp4 = (const float4*)(thrP + (size_t)c * PADF);
    const float* pp = pred + (size_t)rbase * CCLS + c;
    float acc = 0.f;

    // Load 6 quads, masking slots >= cnt to FLT_MAX (they contribute p, cancelled by fS*p).
    // For cnt > 24 all 24 slots are real; the remainder is handled by k_resid.
    float4 tq[NQS];
#pragma unroll
    for (int q = 0; q < NQS; ++q) {
        float4 t = tp4[q];
        t.x = (4 * q + 0 < cnt) ? t.x : FLT_MAX;
        t.y = (4 * q + 1 < cnt) ? t.y : FLT_MAX;
        t.z = (4 * q + 2 < cnt) ? t.z : FLT_MAX;
        t.w = (4 * q + 3 < cnt) ? t.w : FLT_MAX;
        tq[q] = t;
    }
    const float fS = (float)(4 * NQS);

    int r = 0;
#pragma unroll 1
    for (; r + 4 <= rows; r += 4) {
        const float p0 = pp[(size_t)(r + 0) * CCLS];
        const float p1 = pp[(size_t)(r + 1) * CCLS];
        const float p2 = pp[(size_t)(r + 2) * CCLS];
        const float p3 = pp[(size_t)(r + 3) * CCLS];
        float a0 = 0.f, a1 = 0.f, a2 = 0.f, a3 = 0.f;
#pragma unroll
        for (int q = 0; q < NQS; ++q) {
            a0 += MIN4(p0, tq[q]);
            a1 += MIN4(p1, tq[q]);
            a2 += MIN4(p2, tq[q]);
            a3 += MIN4(p3, tq[q]);
        }
        const float2 w0 = rowWT[r + 0], w1 = rowWT[r + 1];
        const float2 w2 = rowWT[r + 2], w3 = rowWT[r + 3];
        const float s0 = (c != __float_as_int(w0.x)) ? w0.y : 0.f;
        const float s1 = (c != __float_as_int(w1.x)) ? w1.y : 0.f;
        const float s2 = (c != __float_as_int(w2.x)) ? w2.y : 0.f;
        const float s3 = (c != __float_as_int(w3.x)) ? w3.y : 0.f;
        acc = fmaf(fmaf(fS, p0, -a0), s0, acc);
        acc = fmaf(fmaf(fS, p1, -a1), s1, acc);
        acc = fmaf(fmaf(fS, p2, -a2), s2, acc);
        acc = fmaf(fmaf(fS, p3, -a3), s3, acc);
    }
    for (; r < rows; ++r) {
        const float p = pp[(size_t)r * CCLS];
        float a = 0.f;
#pragma unroll
        for (int q = 0; q < NQS; ++q) a += MIN4(p, tq[q]);
        const float2 w = rowWT[r];
        const float s = (c != __float_as_int(w.x)) ? w.y : 0.f;
        acc = fmaf(fmaf(fS, p, -a), s, acc);
    }
    acc *= invc;

    for (int o = 32; o; o >>= 1) acc += __shfl_down(acc, o);
    if ((tid & 63) == 0) redL[tid >> 6] = acc;
    __syncthreads();
    if (tid == 0) {
        float ssum = 0.f;
#pragma unroll
        for (int k = 0; k < TPB / 64; ++k) ssum += redL[k];
        part[blockIdx.x] = ssum;          // plain store, no contention
    }
}

// Grid-parallel residual: one thread per row; for each big class c (cnt > 24) add
// sum_{k in [24,cnt)} relu(p - thr_k) * invc * invN[t_i]. Spread across all CUs --
// NOT single-block (R18's mistake). Writes a partial per block (0 if no big classes).
__global__ __launch_bounds__(256) void k_resid(const float* __restrict__ pred,
        const int* __restrict__ target, const float* __restrict__ thrP,
        const int* __restrict__ fill, const int* __restrict__ bigN,
        const int* __restrict__ bigList,
        float* __restrict__ part, int B) {
    __shared__ float redL[4];
    const int tid = threadIdx.x;
    const int i = blockIdx.x * 256 + tid;
    const int nbig = min(bigN[0], MAXBIG);

    float acc = 0.f;
    if (nbig > 0 && i < B) {
        const int t = target[i];
        const float wrow = 1.0f / (float)fill[t];
        for (int bi = 0; bi < nbig; ++bi) {
            const int c = bigList[bi];
            if (c == t) continue;
            const int cnt = min(fill[c], PADF);
            const float invc = 1.0f / (float)fill[c];
            const float p = pred[(size_t)i * CCLS + c];
            float a = 0.f;
            for (int k = 4 * NQS; k < cnt; ++k)
                a += fmaxf(p - thrP[(size_t)c * PADF + k], 0.f);
            acc = fmaf(a, invc * wrow, acc);
        }
    }
    for (int o = 32; o; o >>= 1) acc += __shfl_down(acc, o);
    if ((tid & 63) == 0) redL[tid >> 6] = acc;
    __syncthreads();
    if (tid == 0) part[NBLK + blockIdx.x] = redL[0] + redL[1] + redL[2] + redL[3];
}

// Single-block streaming epilogue: reduce NBLK+NRES partials + E count.
__global__ __launch_bounds__(1024) void k_final(const float* __restrict__ part,
        const int* __restrict__ fill, float* __restrict__ out) {
    __shared__ float wP[16];
    __shared__ int wE[16];
    const int tid = threadIdx.x;
    float sp = 0.f;
    for (int i = tid; i < NBLK + NRES; i += 1024) sp += part[i];
    int se = 0;
    for (int c = tid; c < CCLS; c += 1024) se += (fill[c] > 0) ? 1 : 0;
    for (int o = 32; o; o >>= 1) {
        sp += __shfl_down(sp, o);
        se += __shfl_down(se, o);
    }
    if ((tid & 63) == 0) { wP[tid >> 6] = sp; wE[tid >> 6] = se; }
    __syncthreads();
    if (tid == 0) {
        float tp = 0.f;
        int te = 0;
#pragma unroll
        for (int k = 0; k < 16; ++k) { tp += wP[k]; te += wE[k]; }
        float E = (float)te;
        out[0] = tp / (E * (E - 1.0f));
    }
}

extern "C" void kernel_launch(void* const* d_in, const int* in_sizes, int n_in,
                              void* d_out, int out_size, void* d_ws, size_t ws_size,
                              hipStream_t stream) {
    const float* pred = (const float*)d_in[0];
    const int* target = (const int*)d_in[1];
    const int B = in_sizes[1];  // 12288

    char* ws = (char*)d_ws;
    int* fill    = (int*)(ws + 0);        // 1000 ints
    int* bigN    = (int*)(ws + 4096);     // 1 int
    int* bigList = (int*)(ws + 4160);     // 32 ints
    float* part  = (float*)(ws + 8192);   // NBLK + NRES floats
    float* thrP  = (float*)(ws + 20480);  // 1000*64 floats (256KB)

    const int gb = (B + 255) / 256;
    const int RPB = (B + NRBLK - 1) / NRBLK;

    hipMemsetAsync(ws, 0, 4224, stream);  // fill + bigN (+ list header area)
    k_scatter<<<gb, 256, 0, stream>>>(pred, target, fill, thrP, bigN, bigList, B);
    k_main<<<NBLK, TPB, 0, stream>>>(pred, target, thrP, fill, part, B, RPB);
    k_resid<<<NRES, 256, 0, stream>>>(pred, target, thrP, fill, bigN, bigList, part, B);
    k_final<<<1, 1024, 0, stream>>>(part, fill, (float*)d_out);
}

// Round 22
// 41.047 us; speedup vs baseline: 1.5189x; 1.0727x over previous
//
#include <hip/hip_runtime.h>
#include <float.h>

// loss = (1/(E(E-1))) * sum_{i,j: t_i != t_j} relu(pred[i,t_j] - (f_own[j]-1)) / (N[t_i] N[t_j])
// Identity: sum_{k<S} relu(p - thr_k) = S*p - sum_{k<S} min(p, thr_k) for any S >= cnt
// (FLT_MAX pads contribute exactly 0). Thread = class; thresholds in float4 registers;
// rows stream coalesced; zero inner-loop LDS; no same-address device atomics.
// Diagonal (c == t_i) excluded IN-LOOP. 4 kernels: init, scatter, main, final.
// == R14 configuration: best measured (40.9 us). R15-R20 alternatives all regressed:
//   R15 single-body+tail-reload (L1 thrash, 2.5x), R16 memset+mask (neutral),
//   R17 BODY4T (neutral-worse), R18 serial residual (-21us), R19 resid kernel (neutral),
//   R20 cooperative fusion (fails graph capture).

#define CCLS 1000
#define PADF 64     // float slots per class (fallback supports count <= 64)
#define TPB 256
#define CCH 250     // classes per chunk -> 4 chunks
#define NCH 4
#define NRBLK 512   // row blocks per chunk: RPB = 12288/512 = 24
#define NBLK (NCH * NRBLK)
#define RMAX 32

__global__ void k_init(int* fill, float4* thrP4) {
    int t = blockIdx.x * 256 + threadIdx.x;
    if (t < CCLS) fill[t] = 0;
    if (t < CCLS * 8) {   // pre-pad slots [0,32) of every class with FLT_MAX
        int c = t >> 3, q = t & 7;
        thrP4[c * (PADF / 4) + q] = make_float4(FLT_MAX, FLT_MAX, FLT_MAX, FLT_MAX);
    }
}

__global__ void k_scatter(const float* __restrict__ pred, const int* __restrict__ target,
                          int* fill, float* thrP, int B) {
    int j = blockIdx.x * 256 + threadIdx.x;
    if (j >= B) return;
    int tj = target[j];
    float fo = pred[(size_t)j * CCLS + tj];  // f_own[j]
    int pos = atomicAdd(&fill[tj], 1);       // scattered addresses, low contention
    if (pos < PADF) thrP[tj * PADF + pos] = fo - 1.0f;
}

// Fully-static body: NQ float4 threshold registers, 4-row batches (VGPR < 64).
// Per row: wt = rowWT[r] = (target_as_float, invN[target]); exclude c == target in-loop.
#define BODYQ(NQ)                                                                   \
    {                                                                               \
        float4 tq[NQ];                                                              \
        _Pragma("unroll") for (int q = 0; q < NQ; ++q) tq[q] = tp4[q];              \
        const float fS = (float)(4 * NQ);                                           \
        int r = 0;                                                                  \
        _Pragma("unroll 1") for (; r + 4 <= rows; r += 4) {                         \
            const float p0 = pp[(size_t)(r + 0) * CCLS];                            \
            const float p1 = pp[(size_t)(r + 1) * CCLS];                            \
            const float p2 = pp[(size_t)(r + 2) * CCLS];                            \
            const float p3 = pp[(size_t)(r + 3) * CCLS];                            \
            float a0 = 0.f, a1 = 0.f, a2 = 0.f, a3 = 0.f;                           \
            _Pragma("unroll") for (int q = 0; q < NQ; ++q) {                        \
                a0 += (fminf(p0, tq[q].x) + fminf(p0, tq[q].y))                     \
                    + (fminf(p0, tq[q].z) + fminf(p0, tq[q].w));                    \
                a1 += (fminf(p1, tq[q].x) + fminf(p1, tq[q].y))                     \
                    + (fminf(p1, tq[q].z) + fminf(p1, tq[q].w));                    \
                a2 += (fminf(p2, tq[q].x) + fminf(p2, tq[q].y))                     \
                    + (fminf(p2, tq[q].z) + fminf(p2, tq[q].w));                    \
                a3 += (fminf(p3, tq[q].x) + fminf(p3, tq[q].y))                     \
                    + (fminf(p3, tq[q].z) + fminf(p3, tq[q].w));                    \
            }                                                                       \
            const float2 w0 = rowWT[r + 0], w1 = rowWT[r + 1];                      \
            const float2 w2 = rowWT[r + 2], w3 = rowWT[r + 3];                      \
            const float s0 = (c != __float_as_int(w0.x)) ? w0.y : 0.f;              \
            const float s1 = (c != __float_as_int(w1.x)) ? w1.y : 0.f;              \
            const float s2 = (c != __float_as_int(w2.x)) ? w2.y : 0.f;              \
            const float s3 = (c != __float_as_int(w3.x)) ? w3.y : 0.f;              \
            acc = fmaf(fmaf(fS, p0, -a0), s0, acc);                                 \
            acc = fmaf(fmaf(fS, p1, -a1), s1, acc);                                 \
            acc = fmaf(fmaf(fS, p2, -a2), s2, acc);                                 \
            acc = fmaf(fmaf(fS, p3, -a3), s3, acc);                                 \
        }                                                                           \
        for (; r < rows; ++r) {                                                     \
            const float p = pp[(size_t)r * CCLS];                                   \
            float a = 0.f;                                                          \
            _Pragma("unroll") for (int q = 0; q < NQ; ++q) {                        \
                a += (fminf(p, tq[q].x) + fminf(p, tq[q].y))                        \
                   + (fminf(p, tq[q].z) + fminf(p, tq[q].w));                       \
            }                                                                       \
            const float2 w = rowWT[r];                                              \
            const float s = (c != __float_as_int(w.x)) ? w.y : 0.f;                 \
            acc = fmaf(fmaf(fS, p, -a), s, acc);                                    \
        }                                                                           \
    }

__global__ __launch_bounds__(TPB) void k_main(const float* __restrict__ pred,
        const int* __restrict__ target, const float* __restrict__ thrP,
        const int* __restrict__ fill,
        float* __restrict__ part, int B, int RPB) {
    __shared__ float2 rowWT[RMAX];   // (target_as_float, invN[target]) per row
    __shared__ float redL[TPB / 64];

    const int tid = threadIdx.x;
    const int chunk = blockIdx.x / NRBLK;
    const int rblk = blockIdx.x % NRBLK;
    const int c0 = chunk * CCH;
    const int rbase = rblk * RPB;
    const int rows = min(min(RPB, B - rbase), RMAX);

    for (int r = tid; r < rows; r += TPB) {
        int t = target[rbase + r];
        rowWT[r] = make_float2(__int_as_float(t), 1.0f / (float)fill[t]);
    }
    __syncthreads();

    const int ccS = min(tid, CCH - 1);
    const int c = c0 + ccS;
    const int cntR = fill[c];
    const int cnt = min(cntR, PADF);
    const float invc = (tid < CCH && cntR > 0) ? 1.0f / (float)cntR : 0.f;

    int wmx = cnt;                       // wave-uniform max count
    for (int o = 32; o; o >>= 1) wmx = max(wmx, __shfl_xor(wmx, o));

    const float4* tp4 = (const float4*)(thrP + (size_t)c * PADF);
    const float* pp = pred + (size_t)rbase * CCLS + c;
    float acc = 0.f;

    if (wmx <= 32) {
        const int nq = (wmx + 3) >> 2;   // 1..8, wave-uniform
        switch ((nq + 1) >> 1) {         // 2/4/6/8 quads
            case 0:
            case 1: BODYQ(2) break;
            case 2: BODYQ(4) break;
            case 3: BODYQ(6) break;
            default: BODYQ(8) break;
        }
    } else {
        // correctness fallback (some count in 33..64): per-lane runtime bound, L2-cached
        const float* tg = thrP + (size_t)c * PADF;
        for (int r = 0; r < rows; ++r) {
            const float p = pp[(size_t)r * CCLS];
            float s = 0.f;
            for (int k = 0; k < cnt; ++k) s += fminf(p, tg[k]);
            const float2 w = rowWT[r];
            const float ws = (c != __float_as_int(w.x)) ? w.y : 0.f;
            acc = fmaf(fmaf((float)cnt, p, -s), ws, acc);
        }
    }
    acc *= invc;

    for (int o = 32; o; o >>= 1) acc += __shfl_down(acc, o);
    if ((tid & 63) == 0) redL[tid >> 6] = acc;
    __syncthreads();
    if (tid == 0) {
        float ssum = 0.f;
#pragma unroll
        for (int k = 0; k < TPB / 64; ++k) ssum += redL[k];
        part[blockIdx.x] = ssum;          // plain store, no contention
    }
}

// Single-block streaming epilogue: reduce partials + E count. No dependent chains.
__global__ __launch_bounds__(1024) void k_final(const float* __restrict__ part,
        const int* __restrict__ fill, float* __restrict__ out) {
    __shared__ float wP[16];
    __shared__ int wE[16];
    const int tid = threadIdx.x;
    float sp = 0.f;
    for (int i = tid; i < NBLK; i += 1024) sp += part[i];
    int se = 0;
    for (int c = tid; c < CCLS; c += 1024) se += (fill[c] > 0) ? 1 : 0;
    for (int o = 32; o; o >>= 1) {
        sp += __shfl_down(sp, o);
        se += __shfl_down(se, o);
    }
    if ((tid & 63) == 0) { wP[tid >> 6] = sp; wE[tid >> 6] = se; }
    __syncthreads();
    if (tid == 0) {
        float tp = 0.f;
        int te = 0;
#pragma unroll
        for (int k = 0; k < 16; ++k) { tp += wP[k]; te += wE[k]; }
        float E = (float)te;
        out[0] = tp / (E * (E - 1.0f));
    }
}

extern "C" void kernel_launch(void* const* d_in, const int* in_sizes, int n_in,
                              void* d_out, int out_size, void* d_ws, size_t ws_size,
                              hipStream_t stream) {
    const float* pred = (const float*)d_in[0];
    const int* target = (const int*)d_in[1];
    const int B = in_sizes[1];  // 12288

    char* ws = (char*)d_ws;
    int* fill   = (int*)(ws + 0);        // 1000 ints
    float* part = (float*)(ws + 4096);   // 2048 floats
    float* thrP = (float*)(ws + 16384);  // 1000*64 floats (256KB)

    const int gb = (B + 255) / 256;
    const int RPB = (B + NRBLK - 1) / NRBLK;

    k_init<<<32, 256, 0, stream>>>(fill, (float4*)thrP);
    k_scatter<<<gb, 256, 0, stream>>>(pred, target, fill, thrP, B);
    k_main<<<NBLK, TPB, 0, stream>>>(pred, target, thrP, fill, part, B, RPB);
    k_final<<<1, 1024, 0, stream>>>(part, fill, (float*)d_out);
}